// Round 6
// baseline (241.520 us; speedup 1.0000x reference)
//
#include <hip/hip_runtime.h>
#include <math.h>

#define B 8
#define S 128
#define D 256
#define H 8
#define T 129
#define HD 32
#define NEG_INF -1000000000.0f
#define LN_EPS 1e-5f

// ---------------------------------------------------------------------------
// Kernel 1: ALL pre-attention GEMM work. blockIdx.x slabs:
//   [0,258)   : v  = nv @ Wv + bv       (1032 rows, row-major)
//   [258,514) : U  = desc @ We1_top+be1 (row-major + transposed Ut)
//   [514,770) : V  = desc @ We1_bot     (row-major + transposed Vt)
//   [770,835) : qdkd = nv @ fold(Wq,Wk,wa)+fold(bq,bk)  (1032 x 16)
//   835       : W2ca[c*8+h] fold + econst
// ---------------------------------------------------------------------------
__global__ __launch_bounds__(256) void gemm_all(
    const float* __restrict__ nv, const float* __restrict__ desc,
    const float* __restrict__ Wq, const float* __restrict__ bq,
    const float* __restrict__ Wk, const float* __restrict__ bk,
    const float* __restrict__ Wv, const float* __restrict__ bv,
    const float* __restrict__ We1, const float* __restrict__ be1,
    const float* __restrict__ We2, const float* __restrict__ be2,
    const float* __restrict__ wa,
    float* __restrict__ v, float* __restrict__ U, float* __restrict__ Ut,
    float* __restrict__ V, float* __restrict__ Vt, float* __restrict__ qdkd,
    float* __restrict__ W2ca, float* __restrict__ econst)
{
    const int blk = blockIdx.x;
    const int tid = threadIdx.x;

    __shared__ float xs16[16 * 260];
    __shared__ float wq_s[4096];
    __shared__ float bq_s[16];

    if (blk < 770) {
        const float* X; const float* W; const float* bias; int r0; int mode;
        if (blk < 258)      { X = nv;   W = Wv;        bias = bv;      r0 = blk * 4;         mode = 0; }
        else if (blk < 514) { X = desc; W = We1;       bias = be1;     r0 = (blk - 258) * 4; mode = 1; }
        else                { X = desc; W = We1 + D*D; bias = nullptr; r0 = (blk - 514) * 4; mode = 2; }
        const int c = tid;

        const float* x0 = X + (r0 + 0) * D;
        const float* x1 = X + (r0 + 1) * D;
        const float* x2 = X + (r0 + 2) * D;
        const float* x3 = X + (r0 + 3) * D;

        float acc0 = 0.f, acc1 = 0.f, acc2 = 0.f, acc3 = 0.f;
        float w[8], nw[8];
        #pragma unroll
        for (int q = 0; q < 8; ++q) w[q] = W[q * D + c];

        for (int kk = 0; kk < 256; kk += 8) {
            const int kn = kk + 8;
            if (kn < 256) {
                #pragma unroll
                for (int q = 0; q < 8; ++q) nw[q] = W[(kn + q) * D + c];
            }
            float xv0[8], xv1[8], xv2[8], xv3[8];
            *(float4*)&xv0[0] = *(const float4*)(x0 + kk);
            *(float4*)&xv0[4] = *(const float4*)(x0 + kk + 4);
            *(float4*)&xv1[0] = *(const float4*)(x1 + kk);
            *(float4*)&xv1[4] = *(const float4*)(x1 + kk + 4);
            *(float4*)&xv2[0] = *(const float4*)(x2 + kk);
            *(float4*)&xv2[4] = *(const float4*)(x2 + kk + 4);
            *(float4*)&xv3[0] = *(const float4*)(x3 + kk);
            *(float4*)&xv3[4] = *(const float4*)(x3 + kk + 4);
            #pragma unroll
            for (int q = 0; q < 8; ++q) {
                acc0 = fmaf(xv0[q], w[q], acc0);
                acc1 = fmaf(xv1[q], w[q], acc1);
                acc2 = fmaf(xv2[q], w[q], acc2);
                acc3 = fmaf(xv3[q], w[q], acc3);
            }
            if (kn < 256) {
                #pragma unroll
                for (int q = 0; q < 8; ++q) w[q] = nw[q];
            }
        }

        const float bb = bias ? bias[c] : 0.f;
        const float o0 = acc0 + bb, o1 = acc1 + bb, o2 = acc2 + bb, o3 = acc3 + bb;

        if (mode == 0) {
            v[(r0 + 0) * D + c] = o0;
            v[(r0 + 1) * D + c] = o1;
            v[(r0 + 2) * D + c] = o2;
            v[(r0 + 3) * D + c] = o3;
        } else {
            const int b_ = r0 >> 7, rl = r0 & 127;
            float4 tv; tv.x = o0; tv.y = o1; tv.z = o2; tv.w = o3;
            if (mode == 1) {
                U[(r0 + 0) * D + c] = o0;
                U[(r0 + 1) * D + c] = o1;
                U[(r0 + 2) * D + c] = o2;
                U[(r0 + 3) * D + c] = o3;
                *(float4*)&Ut[(b_ * D + c) * S + rl] = tv;
            } else {
                V[(r0 + 0) * D + c] = o0;
                V[(r0 + 1) * D + c] = o1;
                V[(r0 + 2) * D + c] = o2;
                V[(r0 + 3) * D + c] = o3;
                *(float4*)&Vt[(b_ * D + c) * S + rl] = tv;
            }
        }
    } else if (blk < 835) {
        const int r0 = (blk - 770) * 16;
        for (int t = tid; t < 4096; t += 256) {
            const int k = t >> 4, cc = t & 15;
            const float* Wsrc = (cc < 8) ? Wq : Wk;
            const float* wap  = (cc < 8) ? wa : wa + HD;
            const int h = cc & 7;
            float s = 0.f;
            #pragma unroll
            for (int d = 0; d < HD; ++d) s = fmaf(Wsrc[k*D + h*HD + d], wap[d], s);
            wq_s[t] = s;
        }
        if (tid < 16) {
            const float* bsrc = (tid < 8) ? bq : bk;
            const float* wap  = (tid < 8) ? wa : wa + HD;
            const int h = tid & 7;
            float s = 0.f;
            #pragma unroll
            for (int d = 0; d < HD; ++d) s = fmaf(bsrc[h*HD + d], wap[d], s);
            bq_s[tid] = s;
        }
        for (int t = tid; t < 16 * 256; t += 256) {
            const int r = t >> 8, cch = t & 255, rr = r0 + r;
            xs16[r * 260 + cch] = (rr < B*T) ? nv[rr * D + cch] : 0.f;
        }
        __syncthreads();

        const int r = tid >> 4, cc = tid & 15;
        float acc = 0.f;
        for (int kk = 0; kk < 256; kk += 4) {
            const float4 x = *(const float4*)&xs16[r * 260 + kk];
            acc = fmaf(x.x, wq_s[(kk+0)*16 + cc], acc);
            acc = fmaf(x.y, wq_s[(kk+1)*16 + cc], acc);
            acc = fmaf(x.z, wq_s[(kk+2)*16 + cc], acc);
            acc = fmaf(x.w, wq_s[(kk+3)*16 + cc], acc);
        }
        const int rr = r0 + r;
        if (rr < B*T) qdkd[rr * 16 + cc] = acc + bq_s[cc];
    } else {
        for (int t = tid; t < 2048; t += 256) {
            const int cch = t >> 3, h = t & 7;
            float s = 0.f;
            #pragma unroll
            for (int d = 0; d < HD; ++d) s = fmaf(We2[cch*D + h*HD + d], wa[2*HD + d], s);
            W2ca[t] = s;
        }
        if (tid < 8) {
            float s = 0.f;
            #pragma unroll
            for (int d = 0; d < HD; ++d) s = fmaf(be2[tid*HD + d], wa[2*HD + d], s);
            econst[tid] = s;
        }
    }
}

// ---------------------------------------------------------------------------
// Kernel 2: UV cross terms + per-row LN sums.
//  blk < 256: UV[b][r][j] = sum_c U[b][r][c]*V[b][j][c]  (4 rows/block,
//             lane = j coalesced via Vt; U via wave-uniform scalar loads)
//  blk >= 256: per-batch row stats sU,sU2,sV,sV2 and diag uvd[b][j]
// ---------------------------------------------------------------------------
__global__ __launch_bounds__(128) void uv_stats(
    const float* __restrict__ U, const float* __restrict__ V,
    const float* __restrict__ Vt,
    float* __restrict__ UV, float* __restrict__ sU, float* __restrict__ sU2,
    float* __restrict__ sV, float* __restrict__ sV2, float* __restrict__ uvd)
{
    const int blk = blockIdx.x, tid = threadIdx.x;
    if (blk < 256) {
        const int b = blk >> 5, r0 = (blk & 31) * 4;
        const int j = tid;
        const float* vt = Vt + (size_t)b * D * S;
        const float* u0 = U + ((size_t)b*S + r0 + 0) * D;
        const float* u1 = U + ((size_t)b*S + r0 + 1) * D;
        const float* u2 = U + ((size_t)b*S + r0 + 2) * D;
        const float* u3 = U + ((size_t)b*S + r0 + 3) * D;
        float a0 = 0.f, a1 = 0.f, a2 = 0.f, a3 = 0.f;
        for (int c = 0; c < 256; c += 4) {
            const float4 w0 = *(const float4*)(u0 + c);
            const float4 w1 = *(const float4*)(u1 + c);
            const float4 w2 = *(const float4*)(u2 + c);
            const float4 w3 = *(const float4*)(u3 + c);
            const float vv0 = vt[(c+0)*S + j];
            const float vv1 = vt[(c+1)*S + j];
            const float vv2 = vt[(c+2)*S + j];
            const float vv3 = vt[(c+3)*S + j];
            a0 = fmaf(w0.x, vv0, fmaf(w0.y, vv1, fmaf(w0.z, vv2, fmaf(w0.w, vv3, a0))));
            a1 = fmaf(w1.x, vv0, fmaf(w1.y, vv1, fmaf(w1.z, vv2, fmaf(w1.w, vv3, a1))));
            a2 = fmaf(w2.x, vv0, fmaf(w2.y, vv1, fmaf(w2.z, vv2, fmaf(w2.w, vv3, a2))));
            a3 = fmaf(w3.x, vv0, fmaf(w3.y, vv1, fmaf(w3.z, vv2, fmaf(w3.w, vv3, a3))));
        }
        float* uvb = UV + ((size_t)b*S + r0) * S;
        uvb[0*S + j] = a0;
        uvb[1*S + j] = a1;
        uvb[2*S + j] = a2;
        uvb[3*S + j] = a3;
    } else {
        const int b = blk - 256;
        const int lane = tid & 63, w = tid >> 6;
        const int c0 = lane * 4;
        for (int j = w; j < S; j += 2) {
            const float4 u4 = *(const float4*)(U + ((size_t)b*S + j)*D + c0);
            const float4 v4 = *(const float4*)(V + ((size_t)b*S + j)*D + c0);
            float pu  = u4.x + u4.y + u4.z + u4.w;
            float pu2 = fmaf(u4.x,u4.x, fmaf(u4.y,u4.y, fmaf(u4.z,u4.z, u4.w*u4.w)));
            float pv  = v4.x + v4.y + v4.z + v4.w;
            float pv2 = fmaf(v4.x,v4.x, fmaf(v4.y,v4.y, fmaf(v4.z,v4.z, v4.w*v4.w)));
            float pd  = fmaf(u4.x,v4.x, fmaf(u4.y,v4.y, fmaf(u4.z,v4.z, u4.w*v4.w)));
            #pragma unroll
            for (int m = 32; m >= 1; m >>= 1) {
                pu  += __shfl_xor(pu,  m);
                pu2 += __shfl_xor(pu2, m);
                pv  += __shfl_xor(pv,  m);
                pv2 += __shfl_xor(pv2, m);
                pd  += __shfl_xor(pd,  m);
            }
            if (lane == 0) {
                sU [b*S + j] = pu;
                sU2[b*S + j] = pu2;
                sV [b*S + j] = pv;
                sV2[b*S + j] = pv2;
                uvd[b*S + j] = pd;
            }
        }
    }
}

// ---------------------------------------------------------------------------
// Kernel 3 (v4): lane-per-edge, single pass (LN stats precomputed).
// Block = (b*T + i), 512 thr = 8 waves: jh = wid&1 (j = jh*64+lane, 0-based),
// cc = wid>>1 (channels [cc*64, cc*64+64)).
// ---------------------------------------------------------------------------
__global__ __launch_bounds__(512) void edge_attn(
    const float* __restrict__ U, const float* __restrict__ Ut,
    const float* __restrict__ Vt,
    const float* __restrict__ W2ca, const float* __restrict__ econst,
    const float* __restrict__ ln_g, const float* __restrict__ ln_b,
    const float* __restrict__ qdkd, const float* __restrict__ prior,
    const float* __restrict__ v, const float* __restrict__ ba,
    const float* __restrict__ sU, const float* __restrict__ sU2,
    const float* __restrict__ sV, const float* __restrict__ sV2,
    const float* __restrict__ UV, const float* __restrict__ uvd,
    float* __restrict__ out_basis, float* __restrict__ out_attn)
{
    const int bid = blockIdx.x;
    const int b = bid / T, i = bid % T;
    const int tid = threadIdx.x, lane = tid & 63, wid = tid >> 6;
    const int jh = wid & 1, cc = wid >> 1;
    const int j = jh * 64 + lane;          // 0..127 (edge col = j+1)
    const int cbase = cc * 64;

    __shared__ float part[4][8][128];
    __shared__ float pat[8][128];

    const float* vtb = Vt + (size_t)b * D * S;
    const float* utb = Ut + (size_t)b * D * S;

    // per-edge LN stats from precomputed sums
    float su_, su2_, cross;
    if (i >= 1) {
        su_  = sU [b*S + i-1];
        su2_ = sU2[b*S + i-1];
        cross = UV[((size_t)b*S + (i-1))*S + j];
    } else {
        su_  = sU [b*S + j];
        su2_ = sU2[b*S + j];
        cross = uvd[b*S + j];
    }
    const float mu  = (su_ + sV[b*S + j]) * (1.f / D);
    const float ey2 = fmaf(2.f, cross, su2_ + sV2[b*S + j]) * (1.f / D);
    const float var = ey2 - mu * mu;
    const float rs  = rsqrtf(var + LN_EPS);

    // single pass: normalize + relu + 8-head dot
    float a0=0.f,a1=0.f,a2=0.f,a3=0.f,a4=0.f,a5=0.f,a6=0.f,a7=0.f;
#define EDGE_BODY(UEXPR)                                                     \
    _Pragma("unroll 4")                                                      \
    for (int c = cbase; c < cbase + 64; ++c) {                               \
        const float y = (UEXPR) + vtb[c*S + j];                              \
        float t = fmaf((y - mu) * rs, ln_g[c], ln_b[c]);                     \
        t = fmaxf(t, 0.f);                                                   \
        const float4 wA = *(const float4*)(W2ca + c*8);                      \
        const float4 wB = *(const float4*)(W2ca + c*8 + 4);                  \
        a0 = fmaf(t, wA.x, a0); a1 = fmaf(t, wA.y, a1);                      \
        a2 = fmaf(t, wA.z, a2); a3 = fmaf(t, wA.w, a3);                      \
        a4 = fmaf(t, wB.x, a4); a5 = fmaf(t, wB.y, a5);                      \
        a6 = fmaf(t, wB.z, a6); a7 = fmaf(t, wB.w, a7);                      \
    }
    if (i >= 1) {
        const float* urow = U + (size_t)(b*S + (i-1))*D;
        EDGE_BODY(urow[c])
    } else {
        EDGE_BODY(utb[c*S + j])
    }
#undef EDGE_BODY

    part[cc][0][j] = a0; part[cc][1][j] = a1;
    part[cc][2][j] = a2; part[cc][3][j] = a3;
    part[cc][4][j] = a4; part[cc][5][j] = a5;
    part[cc][6][j] = a6; part[cc][7][j] = a7;
    __syncthreads();

    // ---- Phase B: softmax (wave = head) ----
    const int h = wid;
    const float ecw = econst[h];
    const float ba0 = ba[0];
    const float qdv = qdkd[(b*T + i)*16 + h];
    const int j1 = lane, j2 = 64 + lane;

    float e1s = part[0][h][j1] + part[1][h][j1] + part[2][h][j1] + part[3][h][j1];
    float e2s = part[0][h][j2] + part[1][h][j2] + part[2][h][j2] + part[3][h][j2];
    float l1 = qdv + qdkd[(b*T + 1 + j1)*16 + 8 + h] + e1s + ecw + ba0;
    float l2 = qdv + qdkd[(b*T + 1 + j2)*16 + 8 + h] + e2s + ecw + ba0;
    if (i >= 1) {
        const float* prow = prior + ((size_t)(b*H + h)*S + (i-1))*S;
        const float p1 = fminf(fmaxf(prow[j1], 1e-6f), 1.f - 1e-6f);
        const float p2 = fminf(fmaxf(prow[j2], 1e-6f), 1.f - 1e-6f);
        l1 += __logf(p1) - __logf(1.f - p1);
        l2 += __logf(p2) - __logf(1.f - p2);
        if (j1 == i - 1) l1 = NEG_INF;
        if (j2 == i - 1) l2 = NEG_INF;
    }

    float m = fmaxf(l1, l2);
    #pragma unroll
    for (int mm = 32; mm >= 1; mm >>= 1) m = fmaxf(m, __shfl_xor(m, mm));
    const float e1 = __expf(l1 - m);
    const float e2 = __expf(l2 - m);
    float s = e1 + e2;
    #pragma unroll
    for (int mm = 32; mm >= 1; mm >>= 1) s += __shfl_xor(s, mm);
    const float inv = 1.f / s;
    const float at1 = e1 * inv, at2 = e2 * inv;

    float* arow = out_attn + (size_t)((b*H + h)*T + i)*T;
    arow[1 + j1] = at1;
    arow[1 + j2] = at2;
    if (lane == 0) arow[0] = 0.f;
    pat[h][j1] = at1;
    pat[h][j2] = at2;
    __syncthreads();

    // ---- Phase C: ctx ----
    const int d = lane & 31, half = lane >> 5;
    float acc = 0.f;
    const float* vb = v + (size_t)(b*T)*D + h*HD + d;
    #pragma unroll 8
    for (int jj = 0; jj < 64; ++jj) {
        const int jc = half * 64 + jj;
        acc = fmaf(pat[h][jc], vb[(size_t)(1 + jc)*D], acc);
    }
    acc += __shfl_xor(acc, 32);
    if (lane < 32)
        out_basis[((size_t)(b*T + i)*H + h)*HD + d] = acc;
}

extern "C" void kernel_launch(void* const* d_in, const int* in_sizes, int n_in,
                              void* d_out, int out_size, void* d_ws, size_t ws_size,
                              hipStream_t stream) {
    const float* desc  = (const float*)d_in[0];
    const float* nv    = (const float*)d_in[1];
    const float* prior = (const float*)d_in[2];
    const float* Wq  = (const float*)d_in[3];
    const float* bq  = (const float*)d_in[4];
    const float* Wk  = (const float*)d_in[5];
    const float* bk  = (const float*)d_in[6];
    const float* Wv  = (const float*)d_in[7];
    const float* bv  = (const float*)d_in[8];
    const float* wa  = (const float*)d_in[9];
    const float* ba  = (const float*)d_in[10];
    const float* We1 = (const float*)d_in[11];
    const float* be1 = (const float*)d_in[12];
    const float* lng = (const float*)d_in[13];
    const float* lnb = (const float*)d_in[14];
    const float* We2 = (const float*)d_in[15];
    const float* be2 = (const float*)d_in[16];

    float* ws = (float*)d_ws;
    float* U    = ws; ws += B*S*D;
    float* Ut   = ws; ws += B*D*S;
    float* V    = ws; ws += B*S*D;
    float* Vt   = ws; ws += B*D*S;
    float* v    = ws; ws += B*T*D;
    float* qdkd = ws; ws += B*T*16;
    float* W2ca = ws; ws += D*H;
    float* ec   = ws; ws += H;
    float* UV   = ws; ws += B*S*S;
    float* sU   = ws; ws += B*S;
    float* sU2  = ws; ws += B*S;
    float* sV   = ws; ws += B*S;
    float* sV2  = ws; ws += B*S;
    float* uvd  = ws; ws += B*S;

    float* out_basis = (float*)d_out;
    float* out_attn  = out_basis + B*T*H*HD;

    gemm_all<<<dim3(836), 256, 0, stream>>>(nv, desc, Wq, bq, Wk, bk, Wv, bv,
                                            We1, be1, We2, be2, wa,
                                            v, U, Ut, V, Vt, qdkd, W2ca, ec);
    uv_stats<<<dim3(264), 128, 0, stream>>>(U, V, Vt, UV, sU, sU2, sV, sV2, uvd);
    edge_attn<<<dim3(B*T), 512, 0, stream>>>(U, Ut, Vt, W2ca, ec, lng, lnb,
                                             qdkd, prior, v, ba,
                                             sU, sU2, sV, sV2, UV, uvd,
                                             out_basis, out_attn);
}

// Round 7
// 179.760 us; speedup vs baseline: 1.3436x; 1.3436x over previous
//
#include <hip/hip_runtime.h>
#include <math.h>

#define B 8
#define S 128
#define D 256
#define H 8
#define T 129
#define HD 32
#define NEG_INF -1000000000.0f
#define LN_EPS 1e-5f

// ---------------------------------------------------------------------------
// Kernel 1: ALL pre-attention GEMM work. blockIdx.x slabs:
//   [0,258)   : v = nv @ Wv + bv          (1032 rows, row-major)
//   [258,514) : U = desc @ We1_top + be1  (row-major) + row stats sU,sU2
//   [514,770) : V = desc @ We1_bot        (row-major + Vt) + row stats sV,sV2
//   [770,835) : qdkd = nv @ fold(Wq,Wk,wa) + fold(bq,bk)   (1032 x 16)
//   835       : W2aT[h*D+c] fold + econst
// Dense slabs: 4 rows x 256 cols, thread = 1 col; X via wave-uniform float4
// loads; W prefetched one 8-k chunk ahead.
// ---------------------------------------------------------------------------
__global__ __launch_bounds__(256) void gemm_all(
    const float* __restrict__ nv, const float* __restrict__ desc,
    const float* __restrict__ Wq, const float* __restrict__ bq,
    const float* __restrict__ Wk, const float* __restrict__ bk,
    const float* __restrict__ Wv, const float* __restrict__ bv,
    const float* __restrict__ We1, const float* __restrict__ be1,
    const float* __restrict__ We2, const float* __restrict__ be2,
    const float* __restrict__ wa,
    float* __restrict__ v, float* __restrict__ U, float* __restrict__ V,
    float* __restrict__ Vt, float* __restrict__ qdkd,
    float* __restrict__ W2aT, float* __restrict__ econst,
    float* __restrict__ sU, float* __restrict__ sU2,
    float* __restrict__ sV, float* __restrict__ sV2)
{
    const int blk = blockIdx.x;
    const int tid = threadIdx.x;

    __shared__ float xs16[16 * 260];
    __shared__ float wq_s[4096];
    __shared__ float bq_s[16];
    __shared__ float red[4][8];

    if (blk < 770) {
        const float* X; const float* W; const float* bias; int r0; int mode;
        if (blk < 258)      { X = nv;   W = Wv;        bias = bv;      r0 = blk * 4;         mode = 0; }
        else if (blk < 514) { X = desc; W = We1;       bias = be1;     r0 = (blk - 258) * 4; mode = 1; }
        else                { X = desc; W = We1 + D*D; bias = nullptr; r0 = (blk - 514) * 4; mode = 2; }
        const int c = tid;

        const float* x0 = X + (r0 + 0) * D;
        const float* x1 = X + (r0 + 1) * D;
        const float* x2 = X + (r0 + 2) * D;
        const float* x3 = X + (r0 + 3) * D;

        float acc0 = 0.f, acc1 = 0.f, acc2 = 0.f, acc3 = 0.f;
        float w[8], nw[8];
        #pragma unroll
        for (int q = 0; q < 8; ++q) w[q] = W[q * D + c];

        for (int kk = 0; kk < 256; kk += 8) {
            const int kn = kk + 8;
            if (kn < 256) {
                #pragma unroll
                for (int q = 0; q < 8; ++q) nw[q] = W[(kn + q) * D + c];
            }
            float xv0[8], xv1[8], xv2[8], xv3[8];
            *(float4*)&xv0[0] = *(const float4*)(x0 + kk);
            *(float4*)&xv0[4] = *(const float4*)(x0 + kk + 4);
            *(float4*)&xv1[0] = *(const float4*)(x1 + kk);
            *(float4*)&xv1[4] = *(const float4*)(x1 + kk + 4);
            *(float4*)&xv2[0] = *(const float4*)(x2 + kk);
            *(float4*)&xv2[4] = *(const float4*)(x2 + kk + 4);
            *(float4*)&xv3[0] = *(const float4*)(x3 + kk);
            *(float4*)&xv3[4] = *(const float4*)(x3 + kk + 4);
            #pragma unroll
            for (int q = 0; q < 8; ++q) {
                acc0 = fmaf(xv0[q], w[q], acc0);
                acc1 = fmaf(xv1[q], w[q], acc1);
                acc2 = fmaf(xv2[q], w[q], acc2);
                acc3 = fmaf(xv3[q], w[q], acc3);
            }
            if (kn < 256) {
                #pragma unroll
                for (int q = 0; q < 8; ++q) w[q] = nw[q];
            }
        }

        const float bb = bias ? bias[c] : 0.f;
        const float o0 = acc0 + bb, o1 = acc1 + bb, o2 = acc2 + bb, o3 = acc3 + bb;

        if (mode == 0) {
            if (r0 + 0 < B*T) v[(r0 + 0) * D + c] = o0;
            if (r0 + 1 < B*T) v[(r0 + 1) * D + c] = o1;
            if (r0 + 2 < B*T) v[(r0 + 2) * D + c] = o2;
            if (r0 + 3 < B*T) v[(r0 + 3) * D + c] = o3;
        } else {
            if (mode == 1) {
                U[(r0 + 0) * D + c] = o0;
                U[(r0 + 1) * D + c] = o1;
                U[(r0 + 2) * D + c] = o2;
                U[(r0 + 3) * D + c] = o3;
            } else {
                V[(r0 + 0) * D + c] = o0;
                V[(r0 + 1) * D + c] = o1;
                V[(r0 + 2) * D + c] = o2;
                V[(r0 + 3) * D + c] = o3;
                const int b_ = r0 >> 7, rl = r0 & 127;
                float4 tv; tv.x = o0; tv.y = o1; tv.z = o2; tv.w = o3;
                *(float4*)&Vt[((size_t)b_ * D + c) * S + rl] = tv;
            }
            // ---- per-row sum / sum-of-squares epilogue ----
            float s0 = o0, s1 = o1, s2 = o2, s3 = o3;
            float q0 = o0*o0, q1 = o1*o1, q2 = o2*o2, q3 = o3*o3;
            #pragma unroll
            for (int m = 32; m >= 1; m >>= 1) {
                s0 += __shfl_xor(s0, m); q0 += __shfl_xor(q0, m);
                s1 += __shfl_xor(s1, m); q1 += __shfl_xor(q1, m);
                s2 += __shfl_xor(s2, m); q2 += __shfl_xor(q2, m);
                s3 += __shfl_xor(s3, m); q3 += __shfl_xor(q3, m);
            }
            const int wv = tid >> 6;
            if ((tid & 63) == 0) {
                red[wv][0] = s0; red[wv][1] = s1; red[wv][2] = s2; red[wv][3] = s3;
                red[wv][4] = q0; red[wv][5] = q1; red[wv][6] = q2; red[wv][7] = q3;
            }
            __syncthreads();
            if (tid < 4) {
                const float ss = red[0][tid] + red[1][tid] + red[2][tid] + red[3][tid];
                const float qq = red[0][4+tid] + red[1][4+tid] + red[2][4+tid] + red[3][4+tid];
                const int row = r0 + tid;
                if (mode == 1) { sU[row] = ss; sU2[row] = qq; }
                else           { sV[row] = ss; sV2[row] = qq; }
            }
        }
    } else if (blk < 835) {
        // ---------------- qdkd slab (self-folding) ----------------
        const int r0 = (blk - 770) * 16;
        for (int t = tid; t < 4096; t += 256) {
            const int k = t >> 4, cc = t & 15;
            const float* Wsrc = (cc < 8) ? Wq : Wk;
            const float* wap  = (cc < 8) ? wa : wa + HD;
            const int h = cc & 7;
            float s = 0.f;
            #pragma unroll
            for (int d = 0; d < HD; ++d) s = fmaf(Wsrc[k*D + h*HD + d], wap[d], s);
            wq_s[t] = s;
        }
        if (tid < 16) {
            const float* bsrc = (tid < 8) ? bq : bk;
            const float* wap  = (tid < 8) ? wa : wa + HD;
            const int h = tid & 7;
            float s = 0.f;
            #pragma unroll
            for (int d = 0; d < HD; ++d) s = fmaf(bsrc[h*HD + d], wap[d], s);
            bq_s[tid] = s;
        }
        for (int t = tid; t < 16 * 256; t += 256) {
            const int r = t >> 8, cch = t & 255, rr = r0 + r;
            xs16[r * 260 + cch] = (rr < B*T) ? nv[rr * D + cch] : 0.f;
        }
        __syncthreads();

        const int r = tid >> 4, cc = tid & 15;
        float acc = 0.f;
        for (int kk = 0; kk < 256; kk += 4) {
            const float4 x = *(const float4*)&xs16[r * 260 + kk];
            acc = fmaf(x.x, wq_s[(kk+0)*16 + cc], acc);
            acc = fmaf(x.y, wq_s[(kk+1)*16 + cc], acc);
            acc = fmaf(x.z, wq_s[(kk+2)*16 + cc], acc);
            acc = fmaf(x.w, wq_s[(kk+3)*16 + cc], acc);
        }
        const int rr = r0 + r;
        if (rr < B*T) qdkd[rr * 16 + cc] = acc + bq_s[cc];
    } else {
        // ---------------- W2aT fold + econst ----------------
        for (int t = tid; t < 2048; t += 256) {
            const int h = t >> 8, cch = t & 255;
            float s = 0.f;
            #pragma unroll
            for (int d = 0; d < HD; ++d) s = fmaf(We2[cch*D + h*HD + d], wa[2*HD + d], s);
            W2aT[h*D + cch] = s;
        }
        if (tid < 8) {
            float s = 0.f;
            #pragma unroll
            for (int d = 0; d < HD; ++d) s = fmaf(be2[tid*HD + d], wa[2*HD + d], s);
            econst[tid] = s;
        }
    }
}

// ---------------------------------------------------------------------------
// Kernel 2: UV[b][r][j] = U[b,r,:] . V[b,j,:]  (one row per block, K split 2)
// ---------------------------------------------------------------------------
__global__ __launch_bounds__(256) void uv_gemm(
    const float* __restrict__ U, const float* __restrict__ Vt,
    float* __restrict__ UV)
{
    const int br = blockIdx.x;              // b*S + r
    const int b  = br >> 7;
    const int j  = threadIdx.x & 127, kh = threadIdx.x >> 7;
    const float* urow = U + (size_t)br * D + kh * 128;
    const float* vt   = Vt + (size_t)b * D * S + (size_t)kh * 128 * S;

    float acc = 0.f;
    #pragma unroll 8
    for (int c = 0; c < 128; c += 4) {
        const float4 u4 = *(const float4*)(urow + c);
        acc = fmaf(u4.x, vt[(c+0)*S + j], acc);
        acc = fmaf(u4.y, vt[(c+1)*S + j], acc);
        acc = fmaf(u4.z, vt[(c+2)*S + j], acc);
        acc = fmaf(u4.w, vt[(c+3)*S + j], acc);
    }
    __shared__ float part[2][128];
    part[kh][j] = acc;
    __syncthreads();
    if (kh == 0) UV[(size_t)br * S + j] = part[0][j] + part[1][j];
}

// ---------------------------------------------------------------------------
// Kernel 3 (v5): wave-per-edge (proven R3 body) + precomputed LN stats.
// Block = (b*T + i), 512 thr = 8 waves; wave wid owns j = 1+wid*16 .. +16.
// Lane owns 4 contiguous channels; g/b/W2a/U-row in registers. Head dot via
// value-splitting butterfly. Stats (mu, rs) from sU/sU2/sV/sV2/UV — no LN
// shuffle chain.
// ---------------------------------------------------------------------------
__global__ __launch_bounds__(512) void edge_attn(
    const float* __restrict__ U, const float* __restrict__ V,
    const float* __restrict__ W2aT, const float* __restrict__ econst,
    const float* __restrict__ ln_g, const float* __restrict__ ln_b,
    const float* __restrict__ qdkd, const float* __restrict__ prior,
    const float* __restrict__ v, const float* __restrict__ ba,
    const float* __restrict__ sU, const float* __restrict__ sU2,
    const float* __restrict__ sV, const float* __restrict__ sV2,
    const float* __restrict__ UV,
    float* __restrict__ out_basis, float* __restrict__ out_attn)
{
    const int bid = blockIdx.x;      // b*T + i
    const int b = bid / T, i = bid % T;
    const int tid = threadIdx.x, lane = tid & 63, wid = tid >> 6;
    const int c0 = lane * 4;

    __shared__ float escl[H][132];
    __shared__ float pat[H][132];

    // ---- Phase A: edge scores ----
    const float4 g4 = *(const float4*)(ln_g + c0);
    const float4 b4 = *(const float4*)(ln_b + c0);
    float4 w[H];
    #pragma unroll
    for (int h = 0; h < H; ++h) w[h] = *(const float4*)(W2aT + h*D + c0);
    float4 u4i = make_float4(0.f, 0.f, 0.f, 0.f);
    float su_i = 0.f, su2_i = 0.f;
    const float* UVrow = UV;
    if (i >= 1) {
        u4i   = *(const float4*)(U + (size_t)(b*S + (i-1))*D + c0);
        su_i  = sU [b*S + i-1];
        su2_i = sU2[b*S + i-1];
        UVrow = UV + (size_t)(b*S + (i-1))*S;
    }

    const int hmap = 4*(lane&1) + 2*((lane>>1)&1) + ((lane>>2)&1);
    const float ecl = (lane < 8) ? econst[hmap] : 0.f;

    const int j0 = 1 + wid * 16;
    for (int jj = 0; jj < 16; ++jj) {
        const int j = j0 + jj;                 // 1..128
        if (i >= 1 && j == i) continue;        // wave-uniform skip (never read)

        // per-edge LN stats (no cross-lane reduce)
        const float svj  = sV [b*S + j-1];
        const float sv2j = sV2[b*S + j-1];
        float suv, su2v, cross;
        if (i >= 1) {
            suv = su_i; su2v = su2_i;
            cross = UVrow[j-1];
        } else {
            suv   = sU [b*S + j-1];
            su2v  = sU2[b*S + j-1];
            cross = UV[(size_t)(b*S + j-1)*S + (j-1)];
        }
        const float mu  = (suv + svj) * (1.f / D);
        const float ey2 = fmaf(2.f, cross, su2v + sv2j) * (1.f / D);
        const float rs  = rsqrtf(ey2 - mu*mu + LN_EPS);

        const float4 v4 = *(const float4*)(V + (size_t)(b*S + (j-1))*D + c0);
        float4 u4;
        if (i == 0) u4 = *(const float4*)(U + (size_t)(b*S + (j-1))*D + c0);
        else        u4 = u4i;

        const float y0 = u4.x + v4.x, y1 = u4.y + v4.y;
        const float y2 = u4.z + v4.z, y3 = u4.w + v4.w;

        const float t0 = fmaxf((y0 - mu) * rs * g4.x + b4.x, 0.f);
        const float t1 = fmaxf((y1 - mu) * rs * g4.y + b4.y, 0.f);
        const float t2 = fmaxf((y2 - mu) * rs * g4.z + b4.z, 0.f);
        const float t3 = fmaxf((y3 - mu) * rs * g4.w + b4.w, 0.f);

        float ph[H];
        #pragma unroll
        for (int h = 0; h < H; ++h)
            ph[h] = fmaf(t0, w[h].x, fmaf(t1, w[h].y, fmaf(t2, w[h].z, t3 * w[h].w)));

        // value-splitting butterfly over 8 partials
        {
            const bool hi = (lane & 1);
            float k0 = hi ? ph[4] : ph[0], d0 = hi ? ph[0] : ph[4];
            float k1 = hi ? ph[5] : ph[1], d1 = hi ? ph[1] : ph[5];
            float k2 = hi ? ph[6] : ph[2], d2 = hi ? ph[2] : ph[6];
            float k3 = hi ? ph[7] : ph[3], d3 = hi ? ph[3] : ph[7];
            ph[0] = k0 + __shfl_xor(d0, 1);
            ph[1] = k1 + __shfl_xor(d1, 1);
            ph[2] = k2 + __shfl_xor(d2, 1);
            ph[3] = k3 + __shfl_xor(d3, 1);
        }
        {
            const bool hi = (lane & 2);
            float k0 = hi ? ph[2] : ph[0], d0 = hi ? ph[0] : ph[2];
            float k1 = hi ? ph[3] : ph[1], d1 = hi ? ph[1] : ph[3];
            ph[0] = k0 + __shfl_xor(d0, 2);
            ph[1] = k1 + __shfl_xor(d1, 2);
        }
        {
            const bool hi = (lane & 4);
            float k0 = hi ? ph[1] : ph[0], d0 = hi ? ph[0] : ph[1];
            ph[0] = k0 + __shfl_xor(d0, 4);
        }
        ph[0] += __shfl_xor(ph[0], 8);
        ph[0] += __shfl_xor(ph[0], 16);
        ph[0] += __shfl_xor(ph[0], 32);

        if (lane < 8) escl[hmap][j] = ph[0] + ecl;
    }
    __syncthreads();

    // ---- Phase B: softmax (wave = head) ----
    const int h = wid;
    const int bh = b*H + h;
    const float qdv = qdkd[(b*T + i)*16 + h];
    const float ba0 = ba[0];
    const int j1 = 1 + lane, j2 = 65 + lane;
    const bool v1 = !(i >= 1 && j1 == i);
    const bool v2 = !(i >= 1 && j2 == i);

    float l1 = NEG_INF, l2 = NEG_INF;
    if (v1) {
        l1 = qdv + qdkd[(b*T + j1)*16 + 8 + h] + escl[h][j1] + ba0;
        if (i >= 1) {
            float pr = prior[((size_t)bh*S + (i-1))*S + (j1-1)];
            pr = fminf(fmaxf(pr, 1e-6f), 1.f - 1e-6f);
            l1 += __logf(pr) - __logf(1.f - pr);
        }
    }
    if (v2) {
        l2 = qdv + qdkd[(b*T + j2)*16 + 8 + h] + escl[h][j2] + ba0;
        if (i >= 1) {
            float pr = prior[((size_t)bh*S + (i-1))*S + (j2-1)];
            pr = fminf(fmaxf(pr, 1e-6f), 1.f - 1e-6f);
            l2 += __logf(pr) - __logf(1.f - pr);
        }
    }

    float m = fmaxf(l1, l2);
    #pragma unroll
    for (int mm = 32; mm >= 1; mm >>= 1) m = fmaxf(m, __shfl_xor(m, mm));
    const float e1 = v1 ? __expf(l1 - m) : 0.f;
    const float e2 = v2 ? __expf(l2 - m) : 0.f;
    float s = e1 + e2;
    #pragma unroll
    for (int mm = 32; mm >= 1; mm >>= 1) s += __shfl_xor(s, mm);
    const float inv = 1.f / s;
    const float at1 = e1 * inv, at2 = e2 * inv;

    float* arow = out_attn + (size_t)(bh*T + i)*T;
    arow[j1] = at1;
    arow[j2] = at2;
    if (lane == 0) arow[0] = 0.f;
    pat[h][j1] = at1;
    pat[h][j2] = at2;
    __syncthreads();

    // ---- Phase C: ctx ----
    const int d = lane & 31, half = lane >> 5;
    float acc = 0.f;
    const float* vb = v + (size_t)(b*T)*D + h*HD + d;
    #pragma unroll 8
    for (int jj = 0; jj < 64; ++jj) {
        const int jc = 1 + half*64 + jj;
        acc = fmaf(pat[h][jc], vb[(size_t)jc * D], acc);
    }
    acc += __shfl_xor(acc, 32);
    if (lane < 32)
        out_basis[((size_t)(b*T + i)*H + h)*HD + d] = acc;
}

extern "C" void kernel_launch(void* const* d_in, const int* in_sizes, int n_in,
                              void* d_out, int out_size, void* d_ws, size_t ws_size,
                              hipStream_t stream) {
    const float* desc  = (const float*)d_in[0];
    const float* nv    = (const float*)d_in[1];
    const float* prior = (const float*)d_in[2];
    const float* Wq  = (const float*)d_in[3];
    const float* bq  = (const float*)d_in[4];
    const float* Wk  = (const float*)d_in[5];
    const float* bk  = (const float*)d_in[6];
    const float* Wv  = (const float*)d_in[7];
    const float* bv  = (const float*)d_in[8];
    const float* wa  = (const float*)d_in[9];
    const float* ba  = (const float*)d_in[10];
    const float* We1 = (const float*)d_in[11];
    const float* be1 = (const float*)d_in[12];
    const float* lng = (const float*)d_in[13];
    const float* lnb = (const float*)d_in[14];
    const float* We2 = (const float*)d_in[15];
    const float* be2 = (const float*)d_in[16];

    float* ws = (float*)d_ws;
    float* U    = ws; ws += B*S*D;
    float* V    = ws; ws += B*S*D;
    float* Vt   = ws; ws += B*D*S;
    float* v    = ws; ws += B*T*D;
    float* qdkd = ws; ws += B*T*16;
    float* W2aT = ws; ws += H*D;
    float* ec   = ws; ws += H;
    float* sU   = ws; ws += B*S;
    float* sU2  = ws; ws += B*S;
    float* sV   = ws; ws += B*S;
    float* sV2  = ws; ws += B*S;
    float* UV   = ws; ws += B*S*S;

    float* out_basis = (float*)d_out;
    float* out_attn  = out_basis + B*T*H*HD;

    gemm_all<<<dim3(836), 256, 0, stream>>>(nv, desc, Wq, bq, Wk, bk, Wv, bv,
                                            We1, be1, We2, be2, wa,
                                            v, U, V, Vt, qdkd, W2aT, ec,
                                            sU, sU2, sV, sV2);
    uv_gemm<<<dim3(B*S), 256, 0, stream>>>(U, Vt, UV);
    edge_attn<<<dim3(B*T), 512, 0, stream>>>(U, V, W2aT, ec, lng, lnb,
                                             qdkd, prior, v, ba,
                                             sU, sU2, sV, sV2, UV,
                                             out_basis, out_attn);
}